// Round 5
// baseline (168.006 us; speedup 1.0000x reference)
//
#include <hip/hip_runtime.h>
#include <math.h>

#define NSCORE 200000
#define THR    0.24f
#define ROWCAP 16384
#define BCAP   64
#define NBIN   1024
#define HLO2   0.20f
#define HSC2   1706.6666667f   // NBIN / 0.6
#define COLCAP 256

__device__ __forceinline__ bool better(float av, int ai, float bv, int bi) {
    return (av > bv) || (av == bv && ai < bi);
}

// ---------------- K1: encoder -> normalized bx, stored TRANSPOSED [16][64][4]; zeros cnt ----------------
__global__ __launch_bounds__(128) void k_encoder(
    const float* __restrict__ x,
    const float* __restrict__ w1, const float* __restrict__ b1,
    const float* __restrict__ w2, const float* __restrict__ b2,
    const float* __restrict__ w3, const float* __restrict__ b3,
    const float* __restrict__ w4, const float* __restrict__ b4,
    const float* __restrict__ wf, float* __restrict__ bxT,
    unsigned int* __restrict__ cnt) {
    __shared__ float xs[8][128];      // stride-1 over l -> conflict-free
    __shared__ float sw[1344];        // w1[128] | w2[384]@128 | w3[384]@512 | w4[384]@896 | b1..b4@1280
    __shared__ float sacc[128 * 65];  // padded
    __shared__ float part[2][64];
    __shared__ float vecs[64];
    const int b = blockIdx.x, tid = threadIdx.x;

    if (tid == 0) cnt[b] = 0;         // replaces the memset node (scores runs after us)

    if (tid < 128) sw[tid] = w1[tid];
    for (int i = tid; i < 384; i += 128) {
        sw[128 + i] = w2[i]; sw[512 + i] = w3[i]; sw[896 + i] = w4[i];
    }
    if (tid < 16) {
        sw[1280 + tid] = b1[tid]; sw[1296 + tid] = b2[tid];
        sw[1312 + tid] = b3[tid]; sw[1328 + tid] = b4[tid];
    }
    {
        const float4* xr = (const float4*)(x + (size_t)b * 1024);
        float4 p0 = xr[tid * 2], p1 = xr[tid * 2 + 1];
        xs[0][tid] = p0.x; xs[1][tid] = p0.y; xs[2][tid] = p0.z; xs[3][tid] = p0.w;
        xs[4][tid] = p1.x; xs[5][tid] = p1.y; xs[6][tid] = p1.z; xs[7][tid] = p1.w;
    }
    __syncthreads();

    const int l = tid;
    #pragma unroll 1
    for (int o = 0; o < 64; ++o) {
        int br = o >> 4, oo = o & 15;
        float val;
        if (br == 0) {
            val = sw[1280 + oo];
            #pragma unroll
            for (int c = 0; c < 8; ++c) val = fmaf(sw[oo * 8 + c], xs[c][l], val);
        } else {
            const float* W = sw + 128 + (br - 1) * 384;
            int dil = 1 << (br - 1);
            val = sw[1280 + br * 16 + oo];
            #pragma unroll
            for (int t = 0; t < 3; ++t) {
                int ll = l + dil * (t - 1);
                if (ll >= 0 && ll < 128) {
                    #pragma unroll
                    for (int c = 0; c < 8; ++c)
                        val = fmaf(W[oo * 24 + c * 3 + t], xs[c][ll], val);
                }
            }
        }
        val = 0.5f * val * (1.0f + erff(val * 0.70710678118654752f));  // exact GELU
        sacc[l * 65 + o] = val;
    }
    __syncthreads();
    {
        int o = tid & 63, h = tid >> 6;
        float vs = 0.f;
        #pragma unroll
        for (int j = 0; j < 64; ++j) vs += sacc[(h * 64 + j) * 65 + o];
        part[h][o] = vs;
    }
    __syncthreads();
    if (tid < 64) vecs[tid] = (part[0][tid] + part[1][tid]) * (1.0f / 128.0f);
    __syncthreads();
    if (tid < 64) {
        const float* wr = wf + tid * 64;
        float o = 0.f;
        #pragma unroll
        for (int j = 0; j < 64; ++j) o = fmaf(vecs[j], wr[j], o);
        float mu = o;
        #pragma unroll
        for (int off = 32; off > 0; off >>= 1) mu += __shfl_xor(mu, off);
        mu *= (1.0f / 64.0f);
        float d = o - mu;
        float s2 = d * d;
        #pragma unroll
        for (int off = 32; off > 0; off >>= 1) s2 += __shfl_xor(s2, off);
        float ln = d / sqrtf(s2 * (1.0f / 64.0f) + 1e-5f);
        float n2 = ln * ln;
        #pragma unroll
        for (int off = 32; off > 0; off >>= 1) n2 += __shfl_xor(n2, off);
        float nrm = sqrtf(n2);
        float v = ln / fmaxf(nrm, 1e-12f);
        bxT[(tid >> 2) * 256 + b * 4 + (tid & 3)] = v;   // bxT[i][b][c]
    }
}

// ------- K2: scores, f=4 n-blocking × b-halves(32); LDS-broadcast bx; fused extraction -------
__global__ __launch_bounds__(256, 1) void k_scores(const float* __restrict__ ax,
                                                   const float* __restrict__ bxT,
                                                   unsigned int* __restrict__ cnt,
                                                   float* __restrict__ candv,
                                                   int* __restrict__ candi) {
    __shared__ float4 sbx[1024];          // [16][64] float4 = 16 KB
    __shared__ float sval[64][BCAP];      // 16 KB
    __shared__ int   sidx[64][BCAP];      // 16 KB
    __shared__ unsigned int scnt[64];
    __shared__ unsigned int sbase[64];
    const int tid = threadIdx.x;

    {
        const float4* g = (const float4*)bxT;
        #pragma unroll
        for (int k = 0; k < 4; ++k) sbx[tid + k * 256] = g[tid + k * 256];
    }
    if (tid < 64) scnt[tid] = 0;
    __syncthreads();

    const int base = blockIdx.x * 1024;
    int nq[4]; bool ok[4];
    const float4* ar[4];
    #pragma unroll
    for (int q = 0; q < 4; ++q) {
        nq[q] = base + tid + 256 * q;
        ok[q] = nq[q] < NSCORE;
        ar[q] = (const float4*)(ax + (size_t)(ok[q] ? nq[q] : 0) * 64);
    }

    #pragma unroll 1
    for (int h = 0; h < 2; ++h) {
        float acc[4][32];
        #pragma unroll
        for (int q = 0; q < 4; ++q)
            #pragma unroll
            for (int b = 0; b < 32; ++b) acc[q][b] = 0.f;

        #pragma unroll 1
        for (int i = 0; i < 16; ++i) {
            float4 a0 = ar[0][i], a1 = ar[1][i], a2 = ar[2][i], a3 = ar[3][i];
            const float4* p = &sbx[i * 64 + h * 32];
            #pragma unroll
            for (int b = 0; b < 32; ++b) {
                float4 w = p[b];                  // wave-uniform -> LDS broadcast
                acc[0][b] = fmaf(w.x, a0.x, acc[0][b]);
                acc[0][b] = fmaf(w.y, a0.y, acc[0][b]);
                acc[0][b] = fmaf(w.z, a0.z, acc[0][b]);
                acc[0][b] = fmaf(w.w, a0.w, acc[0][b]);
                acc[1][b] = fmaf(w.x, a1.x, acc[1][b]);
                acc[1][b] = fmaf(w.y, a1.y, acc[1][b]);
                acc[1][b] = fmaf(w.z, a1.z, acc[1][b]);
                acc[1][b] = fmaf(w.w, a1.w, acc[1][b]);
                acc[2][b] = fmaf(w.x, a2.x, acc[2][b]);
                acc[2][b] = fmaf(w.y, a2.y, acc[2][b]);
                acc[2][b] = fmaf(w.z, a2.z, acc[2][b]);
                acc[2][b] = fmaf(w.w, a2.w, acc[2][b]);
                acc[3][b] = fmaf(w.x, a3.x, acc[3][b]);
                acc[3][b] = fmaf(w.y, a3.y, acc[3][b]);
                acc[3][b] = fmaf(w.z, a3.z, acc[3][b]);
                acc[3][b] = fmaf(w.w, a3.w, acc[3][b]);
            }
        }
        // push survivors for this b-half (LDS atomics only)
        #pragma unroll
        for (int b = 0; b < 32; ++b) {
            int row = h * 32 + b;
            #pragma unroll
            for (int q = 0; q < 4; ++q) {
                if (ok[q] && acc[q][b] > THR) {
                    unsigned int p = atomicAdd(&scnt[row], 1u);
                    if (p < BCAP) { sval[row][p] = acc[q][b]; sidx[row][p] = nq[q]; }
                }
            }
        }
    }
    __syncthreads();

    if (tid < 64) {
        unsigned int c = min(scnt[tid], (unsigned int)BCAP);
        sbase[tid] = c ? atomicAdd(&cnt[tid], c) : 0u;
    }
    __syncthreads();

    for (int s = tid; s < 64 * BCAP; s += 256) {
        int b = s >> 6, j = s & (BCAP - 1);
        if (j < (int)min(scnt[b], (unsigned int)BCAP)) {
            unsigned int pos = sbase[b] + (unsigned int)j;
            if (pos < ROWCAP) {
                candv[(size_t)b * ROWCAP + pos] = sval[b][j];
                candi[(size_t)b * ROWCAP + pos] = sidx[b][j];
            }
        }
    }
}

// ------- K3: per-row exact top-16 + fused windows gather/transpose -------
__global__ __launch_bounds__(256) void k_selgat(const unsigned int* __restrict__ cnt,
                                                const float* __restrict__ candv,
                                                const int* __restrict__ candi,
                                                const float* __restrict__ win,
                                                float* __restrict__ out) {
    __shared__ unsigned int hist[NBIN];
    __shared__ float colv[COLCAP];
    __shared__ int   coli[COLCAP];
    __shared__ int   colc;
    __shared__ int   Bsh;
    __shared__ float sv16[16];
    __shared__ int   si16[16];
    __shared__ float sm[1152];
    const int b = blockIdx.x;
    const int t = threadIdx.x;

    for (int i = t; i < NBIN; i += 256) hist[i] = 0;
    if (t == 0) { colc = 0; Bsh = 0; }
    __syncthreads();

    const int cs = (int)min(cnt[b], (unsigned int)ROWCAP);
    for (int i = t; i < cs; i += 256) {
        float v = candv[(size_t)b * ROWCAP + i];
        int bin = (int)((v - HLO2) * HSC2);
        bin = bin < 0 ? 0 : (bin > NBIN - 1 ? NBIN - 1 : bin);
        atomicAdd(&hist[bin], 1u);
    }
    __syncthreads();

    if (t < 64) {   // suffix-scan -> smallest bin B with cumulative-from-top >= 16
        const int base = 1023 - t * 16;
        unsigned int loc[16]; unsigned int sg = 0;
        #pragma unroll
        for (int j = 0; j < 16; ++j) { loc[j] = hist[base - j]; sg += loc[j]; }
        unsigned int cum = sg;
        #pragma unroll
        for (int off = 1; off < 64; off <<= 1) {
            unsigned int u = __shfl_up(cum, off);
            if (t >= off) cum += u;
        }
        unsigned int prev = cum - sg;
        if ((prev < 16u) && (cum >= 16u)) {
            unsigned int run = prev; int Bv = 0;
            #pragma unroll
            for (int j = 0; j < 16; ++j) {
                run += loc[j];
                if (run >= 16u) { Bv = base - j; break; }
            }
            Bsh = Bv;
        }
    }
    __syncthreads();
    const int B = Bsh;

    for (int i = t; i < cs; i += 256) {
        float v = candv[(size_t)b * ROWCAP + i];
        int bin = (int)((v - HLO2) * HSC2);
        bin = bin < 0 ? 0 : (bin > NBIN - 1 ? NBIN - 1 : bin);
        if (bin >= B) {
            int p = atomicAdd(&colc, 1);
            if (p < COLCAP) { colv[p] = v; coli[p] = candi[(size_t)b * ROWCAP + i]; }
        }
    }
    __syncthreads();

    if (t < 64) {
        int m = colc; if (m > COLCAP) m = COLCAP;
        float v0 = (t       < m) ? colv[t]       : -INFINITY;
        float v1 = (t + 64  < m) ? colv[t + 64]  : -INFINITY;
        float v2 = (t + 128 < m) ? colv[t + 128] : -INFINITY;
        float v3 = (t + 192 < m) ? colv[t + 192] : -INFINITY;
        int i0 = (t       < m) ? coli[t]       : 0x7FFFFFFF;
        int i1 = (t + 64  < m) ? coli[t + 64]  : 0x7FFFFFFF;
        int i2 = (t + 128 < m) ? coli[t + 128] : 0x7FFFFFFF;
        int i3 = (t + 192 < m) ? coli[t + 192] : 0x7FFFFFFF;
        for (int r = 0; r < 16; ++r) {
            float bv = v0; int bi = i0; int bs = 0;
            if (better(v1, i1, bv, bi)) { bv = v1; bi = i1; bs = 1; }
            if (better(v2, i2, bv, bi)) { bv = v2; bi = i2; bs = 2; }
            if (better(v3, i3, bv, bi)) { bv = v3; bi = i3; bs = 3; }
            int bl = t;
            #pragma unroll
            for (int off = 32; off > 0; off >>= 1) {
                float ov = __shfl_xor(bv, off);
                int oi = __shfl_xor(bi, off);
                int ol = __shfl_xor(bl, off);
                int os = __shfl_xor(bs, off);
                if (better(ov, oi, bv, bi)) { bv = ov; bi = oi; bl = ol; bs = os; }
            }
            if (t == 0) { sv16[r] = bv; si16[r] = bi; }
            if (t == bl) {
                if (bs == 0) { v0 = -INFINITY; i0 = 0x7FFFFFFF; }
                if (bs == 1) { v1 = -INFINITY; i1 = 0x7FFFFFFF; }
                if (bs == 2) { v2 = -INFINITY; i2 = 0x7FFFFFFF; }
                if (bs == 3) { v3 = -INFINITY; i3 = 0x7FFFFFFF; }
            }
        }
    }
    __syncthreads();
    if (t < 16) out[b * 16 + t] = sv16[t];

    // gather + transpose the 16 windows of this row
    #pragma unroll 1
    for (int w = 0; w < 16; ++w) {
        int idx = si16[w];
        idx = idx < 0 ? 0 : (idx > NSCORE - 1 ? NSCORE - 1 : idx);
        const float* src = win + (size_t)idx * 1152;
        for (int j = t; j < 1152; j += 256) sm[j] = src[j];
        __syncthreads();
        float* dst = out + 1024 + (size_t)(b * 16 + w) * 1152;
        for (int j = t; j < 1152; j += 256) dst[j] = sm[(j % 9) * 128 + (j / 9)];
        __syncthreads();
    }
}

extern "C" void kernel_launch(void* const* d_in, const int* in_sizes, int n_in,
                              void* d_out, int out_size, void* d_ws, size_t ws_size,
                              hipStream_t stream) {
    const float* x   = (const float*)d_in[0];
    const float* ax  = (const float*)d_in[1];
    const float* win = (const float*)d_in[2];
    const float* w1  = (const float*)d_in[3];
    const float* b1  = (const float*)d_in[4];
    const float* w2  = (const float*)d_in[5];
    const float* b2  = (const float*)d_in[6];
    const float* w3  = (const float*)d_in[7];
    const float* b3  = (const float*)d_in[8];
    const float* w4  = (const float*)d_in[9];
    const float* b4  = (const float*)d_in[10];
    const float* wf  = (const float*)d_in[11];
    float* out = (float*)d_out;

    float* wsf = (float*)d_ws;
    float* bxT = wsf;                                         // 4096 floats
    unsigned int* cntp = (unsigned int*)(wsf + 4096);         // 64 uints
    float* candv = (float*)(cntp + 64);                       // 64*16384 floats
    int*   candi = (int*)(candv + (size_t)64 * ROWCAP);       // 64*16384 ints

    hipLaunchKernelGGL(k_encoder, dim3(64), dim3(128), 0, stream,
                       x, w1, b1, w2, b2, w3, b3, w4, b4, wf, bxT, cntp);
    hipLaunchKernelGGL(k_scores, dim3(196), dim3(256), 0, stream,
                       ax, bxT, cntp, candv, candi);
    hipLaunchKernelGGL(k_selgat, dim3(64), dim3(256), 0, stream,
                       cntp, candv, candi, win, out);
}